// Round 1
// baseline (1329.773 us; speedup 1.0000x reference)
//
#include <hip/hip_runtime.h>
#include <math.h>

#define TSEQ   2048
#define BB     2
#define DMODEL 1024
#define NHEAD  16
#define DHEAD  64
#define MROWS  (TSEQ * BB)   // 4096

// ---------------------------------------------------------------------------
// GEMM: C[M][N] = A[M][K] * W[N][K]^T + bias[N]
// mode 0: plain row-major store to C
// mode 1: QKV scatter: col j = c*1024 + h*64 + d ; row m = t*BB + b
//         dst[c] layout [B][H][T][Dh]
// ---------------------------------------------------------------------------
__global__ __launch_bounds__(256)
void gemm_bias_kernel(const float* __restrict__ A, const float* __restrict__ W,
                      const float* __restrict__ bias, float* __restrict__ C,
                      float* __restrict__ Qo, float* __restrict__ Ko,
                      float* __restrict__ Vo,
                      int M, int N, int K, int mode)
{
    __shared__ float As[64][17];
    __shared__ float Bs[64][17];

    const int tid = threadIdx.x;
    const int tx  = tid & 15;
    const int ty  = tid >> 4;
    const int m0  = blockIdx.y * 64;
    const int n0  = blockIdx.x * 64;

    // loader mapping: tid -> (row 0..63, k-offset {0,4,8,12})
    const int lr = tid >> 2;
    const int lk = (tid & 3) * 4;

    float acc[4][4] = {};

    for (int k0 = 0; k0 < K; k0 += 16) {
        float4 a4 = *(const float4*)(A + (size_t)(m0 + lr) * K + k0 + lk);
        float4 b4 = *(const float4*)(W + (size_t)(n0 + lr) * K + k0 + lk);
        As[lr][lk + 0] = a4.x; As[lr][lk + 1] = a4.y;
        As[lr][lk + 2] = a4.z; As[lr][lk + 3] = a4.w;
        Bs[lr][lk + 0] = b4.x; Bs[lr][lk + 1] = b4.y;
        Bs[lr][lk + 2] = b4.z; Bs[lr][lk + 3] = b4.w;
        __syncthreads();
#pragma unroll
        for (int kk = 0; kk < 16; ++kk) {
            float av[4], bv[4];
#pragma unroll
            for (int i = 0; i < 4; ++i) av[i] = As[ty * 4 + i][kk];
#pragma unroll
            for (int j = 0; j < 4; ++j) bv[j] = Bs[tx * 4 + j][kk];
#pragma unroll
            for (int i = 0; i < 4; ++i)
#pragma unroll
                for (int j = 0; j < 4; ++j)
                    acc[i][j] = fmaf(av[i], bv[j], acc[i][j]);
        }
        __syncthreads();
    }

#pragma unroll
    for (int i = 0; i < 4; ++i) {
        const int m = m0 + ty * 4 + i;
#pragma unroll
        for (int j = 0; j < 4; ++j) {
            const int n = n0 + tx * 4 + j;
            const float v = acc[i][j] + bias[n];
            if (mode == 0) {
                C[(size_t)m * N + n] = v;
            } else {
                const int c = n >> 10;          // 0,1,2  (q/k/v)
                const int h = (n >> 6) & 15;
                const int d = n & 63;
                const int t = m >> 1;           // BB == 2
                const int b = m & 1;
                float* dst = (c == 0) ? Qo : (c == 1) ? Ko : Vo;
                dst[(((size_t)b * NHEAD + h) * TSEQ + t) * DHEAD + d] = v;
            }
        }
    }
}

// ---------------------------------------------------------------------------
// Flash attention (fp32), one block = 64 query rows of one (b,h).
// score = (Q.K^T) * 8.0  (reference DIVIDES by softmax_scale = 1/8)
// causal mask: score -= 1e6 where key > query (exactly as reference).
// Fully-masked key blocks are skipped (exp underflows to 0 -> exact).
// ---------------------------------------------------------------------------
__global__ __launch_bounds__(256)
void flash_attn_kernel(const float* __restrict__ Q, const float* __restrict__ K,
                       const float* __restrict__ V, float* __restrict__ AV,
                       const int* __restrict__ causal_p)
{
    __shared__ float Qs[64][65];
    __shared__ float KVs[64][65];   // K block, then reused for V block
    __shared__ float Ss[64][65];
    __shared__ float mrow[64], lrow[64], arow[64];

    const int tid = threadIdx.x;
    const int tx  = tid & 15;
    const int ty  = tid >> 4;
    const int bh  = blockIdx.x;     // b*NHEAD + h
    const int qb  = blockIdx.y;     // query block (64 rows)
    const int b   = bh >> 4;
    const int h   = bh & 15;
    const int causal = causal_p[0];

    const float* Qp = Q + (size_t)bh * TSEQ * DHEAD + (size_t)qb * 64 * DHEAD;
    const float* Kp = K + (size_t)bh * TSEQ * DHEAD;
    const float* Vp = V + (size_t)bh * TSEQ * DHEAD;

    // load Q tile 64x64
    for (int e = tid; e < 1024; e += 256) {
        const int r = e >> 4;
        const int c = (e & 15) * 4;
        float4 v4 = *(const float4*)(Qp + r * 64 + c);
        Qs[r][c] = v4.x; Qs[r][c + 1] = v4.y; Qs[r][c + 2] = v4.z; Qs[r][c + 3] = v4.w;
    }
    if (tid < 64) { mrow[tid] = -3.0e38f; lrow[tid] = 0.0f; }

    float acc[4][4] = {};

    const int kb_end = causal ? qb : (TSEQ / 64 - 1);
    for (int kb = 0; kb <= kb_end; ++kb) {
        __syncthreads();   // Q/prev-PV done before overwriting KVs/Ss

        // load K block
        for (int e = tid; e < 1024; e += 256) {
            const int r = e >> 4;
            const int c = (e & 15) * 4;
            float4 v4 = *(const float4*)(Kp + (size_t)(kb * 64 + r) * DHEAD + c);
            KVs[r][c] = v4.x; KVs[r][c + 1] = v4.y; KVs[r][c + 2] = v4.z; KVs[r][c + 3] = v4.w;
        }
        __syncthreads();

        // S = Q K^T * 8 (+ causal mask on diagonal block)
        float s[4][4] = {};
#pragma unroll
        for (int d = 0; d < 64; ++d) {
            float qv[4], kv[4];
#pragma unroll
            for (int i = 0; i < 4; ++i) qv[i] = Qs[ty * 4 + i][d];
#pragma unroll
            for (int j = 0; j < 4; ++j) kv[j] = KVs[tx * 4 + j][d];
#pragma unroll
            for (int i = 0; i < 4; ++i)
#pragma unroll
                for (int j = 0; j < 4; ++j)
                    s[i][j] = fmaf(qv[i], kv[j], s[i][j]);
        }
        const bool diag = (causal != 0) && (kb == qb);
#pragma unroll
        for (int i = 0; i < 4; ++i)
#pragma unroll
            for (int j = 0; j < 4; ++j) {
                float sv = s[i][j] * 8.0f;
                if (diag && (tx * 4 + j > ty * 4 + i)) sv -= 1.0e6f;
                Ss[ty * 4 + i][tx * 4 + j] = sv;
            }
        __syncthreads();   // Ss ready; KVs free

        // load V block (reuse KVs); row stats in parallel
        for (int e = tid; e < 1024; e += 256) {
            const int r = e >> 4;
            const int c = (e & 15) * 4;
            float4 v4 = *(const float4*)(Vp + (size_t)(kb * 64 + r) * DHEAD + c);
            KVs[r][c] = v4.x; KVs[r][c + 1] = v4.y; KVs[r][c + 2] = v4.z; KVs[r][c + 3] = v4.w;
        }
        if (tid < 64) {
            const float mold = mrow[tid];
            float mx = mold;
            for (int c = 0; c < 64; ++c) mx = fmaxf(mx, Ss[tid][c]);
            mrow[tid] = mx;
            arow[tid] = expf(mold - mx);
        }
        __syncthreads();   // mrow/arow + V ready

        // P = exp(S - m_new)
        for (int e = tid; e < 4096; e += 256) {
            const int r = e >> 6, c = e & 63;
            Ss[r][c] = expf(Ss[r][c] - mrow[r]);
        }
        __syncthreads();   // P ready

        // l update (one wave) + rescale + PV accumulate (all threads)
        if (tid < 64) {
            float rs = 0.0f;
            for (int c = 0; c < 64; ++c) rs += Ss[tid][c];
            lrow[tid] = lrow[tid] * arow[tid] + rs;
        }
        float al[4];
#pragma unroll
        for (int i = 0; i < 4; ++i) al[i] = arow[ty * 4 + i];
#pragma unroll
        for (int i = 0; i < 4; ++i)
#pragma unroll
            for (int j = 0; j < 4; ++j) acc[i][j] *= al[i];
#pragma unroll
        for (int sIdx = 0; sIdx < 64; ++sIdx) {
            float pv[4], vv[4];
#pragma unroll
            for (int i = 0; i < 4; ++i) pv[i] = Ss[ty * 4 + i][sIdx];
#pragma unroll
            for (int j = 0; j < 4; ++j) vv[j] = KVs[sIdx][tx * 4 + j];
#pragma unroll
            for (int i = 0; i < 4; ++i)
#pragma unroll
                for (int j = 0; j < 4; ++j)
                    acc[i][j] = fmaf(pv[i], vv[j], acc[i][j]);
        }
    }
    __syncthreads();   // lrow final

    // write AV in [t][b][h*64+d] layout (rows of the out-proj GEMM)
#pragma unroll
    for (int i = 0; i < 4; ++i) {
        const int qg   = qb * 64 + ty * 4 + i;
        const float il = 1.0f / lrow[ty * 4 + i];
#pragma unroll
        for (int j = 0; j < 4; ++j) {
            const int d = tx * 4 + j;
            AV[((size_t)qg * BB + b) * DMODEL + h * DHEAD + d] = acc[i][j] * il;
        }
    }
}

// ---------------------------------------------------------------------------
extern "C" void kernel_launch(void* const* d_in, const int* in_sizes, int n_in,
                              void* d_out, int out_size, void* d_ws, size_t ws_size,
                              hipStream_t stream)
{
    const float* x      = (const float*)d_in[0];
    const float* qkv_w  = (const float*)d_in[1];
    const float* qkv_b  = (const float*)d_in[2];
    const float* out_w  = (const float*)d_in[3];
    const float* out_b  = (const float*)d_in[4];
    const int*   is_causal = (const int*)d_in[5];

    float* out = (float*)d_out;

    const size_t HSZ = (size_t)BB * NHEAD * TSEQ * DHEAD;  // 4,194,304 elems
    float* wsf = (float*)d_ws;
    float* Q   = wsf;
    float* K   = wsf + HSZ;
    float* V   = wsf + 2 * HSZ;
    float* AV  = wsf + 3 * HSZ;

    // 1) QKV projection + scatter: M=4096, N=3072, K=1024
    gemm_bias_kernel<<<dim3(3 * DMODEL / 64, MROWS / 64), 256, 0, stream>>>(
        x, qkv_w, qkv_b, nullptr, Q, K, V, MROWS, 3 * DMODEL, DMODEL, 1);

    // 2) flash attention: grid (B*H, T/64)
    flash_attn_kernel<<<dim3(BB * NHEAD, TSEQ / 64), 256, 0, stream>>>(
        Q, K, V, AV, is_causal);

    // 3) output projection: M=4096, N=1024, K=1024
    gemm_bias_kernel<<<dim3(DMODEL / 64, MROWS / 64), 256, 0, stream>>>(
        AV, out_w, out_b, out, nullptr, nullptr, nullptr, MROWS, DMODEL, DMODEL, 0);
}

// Round 2
// 252.801 us; speedup vs baseline: 5.2602x; 5.2602x over previous
//
#include <hip/hip_runtime.h>
#include <math.h>

#define TSEQ   2048
#define BB     2
#define DMODEL 1024
#define NHEAD  16
#define DHEAD  64
#define MROWS  (TSEQ * BB)   // 4096

typedef __attribute__((ext_vector_type(8))) _Float16 half8;
typedef __attribute__((ext_vector_type(4))) float    floatx4;
typedef unsigned short u16;

__device__ __forceinline__ u16 f2h(float f) {
    union { _Float16 h; u16 u; } cv;
    cv.h = (_Float16)f;
    return cv.u;
}

__device__ __forceinline__ float rmax16(float x) {
    x = fmaxf(x, __shfl_xor(x, 1));
    x = fmaxf(x, __shfl_xor(x, 2));
    x = fmaxf(x, __shfl_xor(x, 4));
    x = fmaxf(x, __shfl_xor(x, 8));
    return x;
}
__device__ __forceinline__ float rsum16(float x) {
    x += __shfl_xor(x, 1);
    x += __shfl_xor(x, 2);
    x += __shfl_xor(x, 4);
    x += __shfl_xor(x, 8);
    return x;
}

// ---------------------------------------------------------------------------
// fp32 -> fp16 cast, vectorized
// ---------------------------------------------------------------------------
__global__ __launch_bounds__(256)
void cast_f32_f16(const float* __restrict__ in, u16* __restrict__ out, int n4)
{
    int i = blockIdx.x * 256 + threadIdx.x;
    if (i >= n4) return;
    float4 v = ((const float4*)in)[i];
    ushort4 o;
    o.x = f2h(v.x); o.y = f2h(v.y); o.z = f2h(v.z); o.w = f2h(v.w);
    ((ushort4*)out)[i] = o;
}

// ---------------------------------------------------------------------------
// fp16 MFMA GEMM: C[M][N] = A[M][K] * W[N][K]^T + bias[N]
// 128x128 block tile, BK=32, 4 waves each 64x64 (4x4 frags of 16x16x32).
// mode 0: fp32 store to Cout.  mode 1: fp16 scatter to Q/K/V [b][h][t][d].
// ---------------------------------------------------------------------------
__global__ __launch_bounds__(256)
void gemm_f16(const u16* __restrict__ A, const u16* __restrict__ W,
              const float* __restrict__ bias, float* __restrict__ Cout,
              u16* __restrict__ Qo, u16* __restrict__ Ko, u16* __restrict__ Vo,
              int M, int N, int K, int mode)
{
    __shared__ __align__(16) u16 As[128][40];   // 32 k + 8 pad (2-way banks)
    __shared__ __align__(16) u16 Bs[128][40];

    const int tid  = threadIdx.x;
    const int lane = tid & 63;
    const int wv   = tid >> 6;
    const int wm   = wv >> 1, wn = wv & 1;
    const int ln   = lane & 15, lh = lane >> 4;
    const int m0   = blockIdx.y * 128;
    const int n0   = blockIdx.x * 128;

    const floatx4 zero4 = {0.0f, 0.0f, 0.0f, 0.0f};
    floatx4 acc[4][4];
#pragma unroll
    for (int i = 0; i < 4; ++i)
#pragma unroll
        for (int j = 0; j < 4; ++j) acc[i][j] = zero4;

    for (int k0 = 0; k0 < K; k0 += 32) {
        __syncthreads();                 // prior frag reads done
#pragma unroll
        for (int c = 0; c < 2; ++c) {
            int idx = c * 256 + tid;     // 0..511
            int row = idx >> 2;          // 0..127
            int kc  = (idx & 3) * 8;     // 0,8,16,24
            *(uint4*)&As[row][kc] = *(const uint4*)(A + (size_t)(m0 + row) * K + k0 + kc);
            *(uint4*)&Bs[row][kc] = *(const uint4*)(W + (size_t)(n0 + row) * K + k0 + kc);
        }
        __syncthreads();

        half8 a[4], b[4];
#pragma unroll
        for (int i = 0; i < 4; ++i)
            a[i] = *(const half8*)&As[wm * 64 + i * 16 + ln][lh * 8];
#pragma unroll
        for (int j = 0; j < 4; ++j)
            b[j] = *(const half8*)&Bs[wn * 64 + j * 16 + ln][lh * 8];
#pragma unroll
        for (int i = 0; i < 4; ++i)
#pragma unroll
            for (int j = 0; j < 4; ++j)
                acc[i][j] = __builtin_amdgcn_mfma_f32_16x16x32_f16(a[i], b[j], acc[i][j], 0, 0, 0);
    }

    // epilogue: C row = (lane>>4)*4 + p, col = lane&15  (m89-verified layout)
#pragma unroll
    for (int i = 0; i < 4; ++i) {
#pragma unroll
        for (int j = 0; j < 4; ++j) {
            const int col = n0 + wn * 64 + j * 16 + ln;
            const float bc = bias[col];
#pragma unroll
            for (int p = 0; p < 4; ++p) {
                const int row = m0 + wm * 64 + i * 16 + lh * 4 + p;
                const float v = acc[i][j][p] + bc;
                if (mode == 0) {
                    Cout[(size_t)row * N + col] = v;
                } else {
                    const int c = col >> 10;         // 0,1,2 = q,k,v
                    const int h = (col >> 6) & 15;
                    const int d = col & 63;
                    const int t = row >> 1;          // BB == 2
                    const int b = row & 1;
                    u16* dst = (c == 0) ? Qo : (c == 1) ? Ko : Vo;
                    dst[(((size_t)b * NHEAD + h) * TSEQ + t) * DHEAD + d] = f2h(v);
                }
            }
        }
    }
}

// ---------------------------------------------------------------------------
// MFMA flash attention (fp16 in, fp32 acc).
// Block = 64 q-rows of one (b,h); 4 waves x 16 q-rows.
// score = (Q.K^T) * 8 (reference divides by 1/8); causal: score -= 1e6.
// P goes C-layout -> LDS -> A-layout (m120 pattern). V transposed into LDS
// with 8-block XOR swizzle (kills structural 8-way write conflict).
// ---------------------------------------------------------------------------
__global__ __launch_bounds__(256)
void flash_f16(const u16* __restrict__ Q, const u16* __restrict__ K,
               const u16* __restrict__ V, u16* __restrict__ AV,
               const int* __restrict__ causal_p)
{
    __shared__ __align__(16) u16 Qs[64][72];
    __shared__ __align__(16) u16 Ks[64][72];
    __shared__ __align__(16) u16 Vt[64][72];   // transposed: [d][key^swz]
    __shared__ __align__(16) u16 Ps[64][72];

    const int tid  = threadIdx.x;
    const int lane = tid & 63;
    const int wv   = tid >> 6;
    const int ln   = lane & 15, lh = lane >> 4;
    const int bh   = blockIdx.x;                // b*16 + h
    const int qb   = blockIdx.y;
    const int b    = bh >> 4;
    const int h    = bh & 15;
    const int causal = causal_p[0];

    const u16* Qg = Q + (size_t)bh * TSEQ * DHEAD;
    const u16* Kg = K + (size_t)bh * TSEQ * DHEAD;
    const u16* Vg = V + (size_t)bh * TSEQ * DHEAD;

    // load Q tile 64x64
#pragma unroll
    for (int c = 0; c < 2; ++c) {
        int idx = c * 256 + tid;
        int row = idx >> 3;
        int c8  = (idx & 7) * 8;
        *(uint4*)&Qs[row][c8] = *(const uint4*)(Qg + (size_t)(qb * 64 + row) * DHEAD + c8);
    }
    __syncthreads();

    const int qr0 = wv * 16;
    const half8 aQ0 = *(const half8*)&Qs[qr0 + ln][lh * 8];
    const half8 aQ1 = *(const half8*)&Qs[qr0 + ln][32 + lh * 8];

    const floatx4 zero4 = {0.0f, 0.0f, 0.0f, 0.0f};
    floatx4 o[4];
#pragma unroll
    for (int j = 0; j < 4; ++j) o[j] = zero4;
    float m_i[4], l_i[4];
#pragma unroll
    for (int r = 0; r < 4; ++r) { m_i[r] = -3.0e38f; l_i[r] = 0.0f; }

    const int kb_end = causal ? qb : (TSEQ / 64 - 1);
    for (int kb = 0; kb <= kb_end; ++kb) {
        __syncthreads();   // prior reads of Ks/Vt done

        // stage K tile (row-major)
#pragma unroll
        for (int c = 0; c < 2; ++c) {
            int idx = c * 256 + tid;
            int row = idx >> 3;
            int c8  = (idx & 7) * 8;
            *(uint4*)&Ks[row][c8] = *(const uint4*)(Kg + (size_t)(kb * 64 + row) * DHEAD + c8);
        }
        // stage V transposed with xor swizzle
#pragma unroll
        for (int c = 0; c < 2; ++c) {
            int idx = c * 256 + tid;
            int key = idx >> 3;
            int c8  = (idx & 7) * 8;
            uint4 vv = *(const uint4*)(Vg + (size_t)(kb * 64 + key) * DHEAD + c8);
            const u16* pv = (const u16*)&vv;
#pragma unroll
            for (int e = 0; e < 8; ++e) {
                int rr = c8 + e;
                Vt[rr][key ^ ((rr >> 3) << 3)] = pv[e];
            }
        }
        __syncthreads();

        // S = Q K^T  (4 key-frags x 2 k-steps)
        floatx4 s[4];
#pragma unroll
        for (int j = 0; j < 4; ++j) {
            half8 bk0 = *(const half8*)&Ks[j * 16 + ln][lh * 8];
            half8 bk1 = *(const half8*)&Ks[j * 16 + ln][32 + lh * 8];
            floatx4 z = zero4;
            z = __builtin_amdgcn_mfma_f32_16x16x32_f16(aQ0, bk0, z, 0, 0, 0);
            z = __builtin_amdgcn_mfma_f32_16x16x32_f16(aQ1, bk1, z, 0, 0, 0);
            s[j] = z;
        }

        // scale by 8, causal mask on diagonal block (exactly like reference)
        const bool diag = (causal != 0) && (kb == qb);
        float sv[4][4];
#pragma unroll
        for (int j = 0; j < 4; ++j) {
#pragma unroll
            for (int r = 0; r < 4; ++r) {
                float x = s[j][r] * 8.0f;
                if (diag && (j * 16 + ln > qr0 + lh * 4 + r)) x -= 1.0e6f;
                sv[j][r] = x;
            }
        }

        // online softmax stats (rows live in lane>>4 groups; 16-lane shuffles)
        float mnew[4], alpha[4];
#pragma unroll
        for (int r = 0; r < 4; ++r) {
            float mx = m_i[r];
#pragma unroll
            for (int j = 0; j < 4; ++j) mx = fmaxf(mx, sv[j][r]);
            mx = rmax16(mx);
            mnew[r] = mx;
            alpha[r] = __expf(m_i[r] - mx);
            m_i[r] = mx;
        }
        float p[4][4];
#pragma unroll
        for (int j = 0; j < 4; ++j)
#pragma unroll
            for (int r = 0; r < 4; ++r) p[j][r] = __expf(sv[j][r] - mnew[r]);
#pragma unroll
        for (int r = 0; r < 4; ++r) {
            float t = p[0][r] + p[1][r] + p[2][r] + p[3][r];
            t = rsum16(t);
            l_i[r] = l_i[r] * alpha[r] + t;
        }
#pragma unroll
        for (int j = 0; j < 4; ++j)
#pragma unroll
            for (int r = 0; r < 4; ++r) o[j][r] *= alpha[r];

        // P: C-layout -> LDS (wave-private rows; no barrier needed)
#pragma unroll
        for (int j = 0; j < 4; ++j)
#pragma unroll
            for (int r = 0; r < 4; ++r)
                Ps[qr0 + lh * 4 + r][j * 16 + ln] = f2h(p[j][r]);

        half8 aP0 = *(const half8*)&Ps[qr0 + ln][lh * 8];
        half8 aP1 = *(const half8*)&Ps[qr0 + ln][32 + lh * 8];

        // O += P V   (4 d-frags x 2 k-steps over keys)
#pragma unroll
        for (int j = 0; j < 4; ++j) {
            int rowd = j * 16 + ln;
            int sw   = (rowd >> 3) << 3;
            half8 bv0 = *(const half8*)&Vt[rowd][(lh * 8) ^ sw];
            half8 bv1 = *(const half8*)&Vt[rowd][(32 + lh * 8) ^ sw];
            o[j] = __builtin_amdgcn_mfma_f32_16x16x32_f16(aP0, bv0, o[j], 0, 0, 0);
            o[j] = __builtin_amdgcn_mfma_f32_16x16x32_f16(aP1, bv1, o[j], 0, 0, 0);
        }
    }

    // epilogue: AV[t][b][h*64+d] as fp16 rows for the out-proj GEMM
#pragma unroll
    for (int r = 0; r < 4; ++r) {
        const float il = 1.0f / l_i[r];
        const int qrow = qb * 64 + qr0 + lh * 4 + r;
#pragma unroll
        for (int j = 0; j < 4; ++j) {
            const int d = j * 16 + ln;
            AV[((size_t)qrow * BB + b) * DMODEL + h * 64 + d] = f2h(o[j][r] * il);
        }
    }
}

// ---------------------------------------------------------------------------
extern "C" void kernel_launch(void* const* d_in, const int* in_sizes, int n_in,
                              void* d_out, int out_size, void* d_ws, size_t ws_size,
                              hipStream_t stream)
{
    const float* x      = (const float*)d_in[0];
    const float* qkv_w  = (const float*)d_in[1];
    const float* qkv_b  = (const float*)d_in[2];
    const float* out_w  = (const float*)d_in[3];
    const float* out_b  = (const float*)d_in[4];
    const int*   is_causal = (const int*)d_in[5];
    float* out = (float*)d_out;

    u16* ws   = (u16*)d_ws;
    u16* xb   = ws;                       // 4096*1024
    u16* wqkv = xb   + (size_t)4194304;   // 3072*1024
    u16* wout = wqkv + (size_t)3145728;   // 1024*1024
    u16* Qh   = wout + (size_t)1048576;   // 2*16*2048*64
    u16* Kh   = Qh   + (size_t)4194304;
    u16* Vh   = Kh   + (size_t)4194304;
    u16* AVh  = Vh   + (size_t)4194304;   // 4096*1024

    cast_f32_f16<<<4096, 256, 0, stream>>>(x,     xb,   1048576);
    cast_f32_f16<<<3072, 256, 0, stream>>>(qkv_w, wqkv,  786432);
    cast_f32_f16<<<1024, 256, 0, stream>>>(out_w, wout,  262144);

    // QKV projection: M=4096, N=3072, K=1024 (scatter epilogue)
    gemm_f16<<<dim3(3 * DMODEL / 128, MROWS / 128), 256, 0, stream>>>(
        xb, wqkv, qkv_b, nullptr, Qh, Kh, Vh, MROWS, 3 * DMODEL, DMODEL, 1);

    // flash attention: grid (B*H, T/64)
    flash_f16<<<dim3(BB * NHEAD, TSEQ / 64), 256, 0, stream>>>(
        Qh, Kh, Vh, AVh, is_causal);

    // output projection: M=4096, N=1024, K=1024 (fp32 out)
    gemm_f16<<<dim3(DMODEL / 128, MROWS / 128), 256, 0, stream>>>(
        AVh, wout, out_b, out, nullptr, nullptr, nullptr, MROWS, DMODEL, DMODEL, 0);
}

// Round 4
// 232.329 us; speedup vs baseline: 5.7237x; 1.0881x over previous
//
#include <hip/hip_runtime.h>
#include <math.h>

#define TSEQ   2048
#define BB     2
#define DMODEL 1024
#define NHEAD  16
#define DHEAD  64
#define MROWS  (TSEQ * BB)   // 4096
#define NQB    (TSEQ / 64)   // 32 query tiles per (b,h)

typedef __attribute__((ext_vector_type(8))) _Float16 half8;
typedef __attribute__((ext_vector_type(4))) float    floatx4;
typedef unsigned short u16;

__device__ __forceinline__ u16 f2h(float f) {
    union { _Float16 h; u16 u; } cv;
    cv.h = (_Float16)f;
    return cv.u;
}

__device__ __forceinline__ void async_cp16(const u16* g, u16* l) {
    __builtin_amdgcn_global_load_lds(
        (const __attribute__((address_space(1))) unsigned int*)g,
        (__attribute__((address_space(3))) unsigned int*)l, 16, 0, 0);
}

__device__ __forceinline__ float rmax16(float x) {
    x = fmaxf(x, __shfl_xor(x, 1));
    x = fmaxf(x, __shfl_xor(x, 2));
    x = fmaxf(x, __shfl_xor(x, 4));
    x = fmaxf(x, __shfl_xor(x, 8));
    return x;
}
__device__ __forceinline__ float rsum16(float x) {
    x += __shfl_xor(x, 1);
    x += __shfl_xor(x, 2);
    x += __shfl_xor(x, 4);
    x += __shfl_xor(x, 8);
    return x;
}

// ---------------------------------------------------------------------------
// one-launch fp32 -> fp16 cast of x, qkv_w, out_w
// float4 units: x 1048576, qkv_w 786432, out_w 262144 (total 2097152)
// ---------------------------------------------------------------------------
__global__ __launch_bounds__(256)
void cast3_f32_f16(const float* __restrict__ a, u16* __restrict__ oa,
                   const float* __restrict__ b, u16* __restrict__ ob,
                   const float* __restrict__ c, u16* __restrict__ oc)
{
    int i = blockIdx.x * 256 + threadIdx.x;
    const float* src; u16* dst; int off;
    if (i < 1048576)      { src = a; dst = oa; off = 0; }
    else if (i < 1835008) { src = b; dst = ob; off = 1048576; }
    else                  { src = c; dst = oc; off = 1835008; }
    int j = i - off;
    float4 v = ((const float4*)src)[j];
    ushort4 o;
    o.x = f2h(v.x); o.y = f2h(v.y); o.z = f2h(v.z); o.w = f2h(v.w);
    ((ushort4*)dst)[j] = o;
}

// ---------------------------------------------------------------------------
// fp16 MFMA GEMM: C[M][N] = A[M][K] * W[N][K]^T + bias[N]
// 128x128 tile, BK=64, global_load_lds (16B) staging into XOR-swizzled LDS:
//   LDS slot (row, s) holds global 8-elem chunk  g = s ^ (row & 7)
// -> staging DMA is lane-sequential; b128 frag reads are conflict-free.
// mode 0: fp32 store.  mode 1: fp16 scatter to Q/K/V [b][h][t][d].
// ---------------------------------------------------------------------------
__global__ __launch_bounds__(256)
void gemm_f16(const u16* __restrict__ A, const u16* __restrict__ W,
              const float* __restrict__ bias, float* __restrict__ Cout,
              u16* __restrict__ Qo, u16* __restrict__ Ko, u16* __restrict__ Vo,
              int M, int N, int K, int mode)
{
    __shared__ __align__(16) u16 As[128][64];
    __shared__ __align__(16) u16 Bs[128][64];

    const int tid  = threadIdx.x;
    const int lane = tid & 63;
    const int wv   = tid >> 6;
    const int wm   = wv >> 1, wn = wv & 1;
    const int ln   = lane & 15, lh = lane >> 4;
    const int m0   = blockIdx.y * 128;
    const int n0   = blockIdx.x * 128;

    const int srow  = wv * 32 + (lane >> 3);   // + t*8, t = 0..3
    const int sslot = lane & 7;

    const floatx4 zero4 = {0.0f, 0.0f, 0.0f, 0.0f};
    floatx4 acc[4][4];
#pragma unroll
    for (int i = 0; i < 4; ++i)
#pragma unroll
        for (int j = 0; j < 4; ++j) acc[i][j] = zero4;

    for (int k0 = 0; k0 < K; k0 += 64) {
        __syncthreads();                     // prior frag reads done
#pragma unroll
        for (int t = 0; t < 4; ++t) {
            const int row = srow + t * 8;
            const int g   = sslot ^ (row & 7);
            async_cp16(A + (size_t)(m0 + row) * K + k0 + g * 8, &As[row][sslot * 8]);
            async_cp16(W + (size_t)(n0 + row) * K + k0 + g * 8, &Bs[row][sslot * 8]);
        }
        __syncthreads();                     // barrier drains vmcnt -> DMA done

#pragma unroll
        for (int ks = 0; ks < 2; ++ks) {
            half8 a[4], b[4];
#pragma unroll
            for (int i = 0; i < 4; ++i) {
                const int row = wm * 64 + i * 16 + ln;
                a[i] = *(const half8*)&As[row][(((ks << 2) | lh) ^ (row & 7)) * 8];
            }
#pragma unroll
            for (int j = 0; j < 4; ++j) {
                const int row = wn * 64 + j * 16 + ln;
                b[j] = *(const half8*)&Bs[row][(((ks << 2) | lh) ^ (row & 7)) * 8];
            }
#pragma unroll
            for (int i = 0; i < 4; ++i)
#pragma unroll
                for (int j = 0; j < 4; ++j)
                    acc[i][j] = __builtin_amdgcn_mfma_f32_16x16x32_f16(a[i], b[j], acc[i][j], 0, 0, 0);
        }
    }

    // epilogue: C row = lh*4 + p, col = ln  (m89-verified, dtype-independent)
#pragma unroll
    for (int i = 0; i < 4; ++i) {
#pragma unroll
        for (int j = 0; j < 4; ++j) {
            const int col = n0 + wn * 64 + j * 16 + ln;
            const float bc = bias[col];
#pragma unroll
            for (int p = 0; p < 4; ++p) {
                const int row = m0 + wm * 64 + i * 16 + lh * 4 + p;
                const float v = acc[i][j][p] + bc;
                if (mode == 0) {
                    Cout[(size_t)row * N + col] = v;
                } else {
                    const int c = col >> 10;         // 0,1,2 = q,k,v
                    const int h = (col >> 6) & 15;
                    const int d = col & 63;
                    const int t = row >> 1;          // BB == 2
                    const int b = row & 1;
                    u16* dst = (c == 0) ? Qo : (c == 1) ? Ko : Vo;
                    dst[(((size_t)b * NHEAD + h) * TSEQ + t) * DHEAD + d] = f2h(v);
                }
            }
        }
    }
}

// ---------------------------------------------------------------------------
// MFMA flash attention, work-balanced + prefetched.
// Block = pair of 64-row q-tiles {p, 31-p} of one (b,h) -> uniform 33 iters.
// Softmax in exp2 domain: p = exp2(s*8*log2e - m'); identical softmax value.
// K/V for kb+1 prefetched into registers during compute of kb.
// ---------------------------------------------------------------------------
__global__ __launch_bounds__(256)
void flash_f16(const u16* __restrict__ Q, const u16* __restrict__ K,
               const u16* __restrict__ V, u16* __restrict__ AV,
               const int* __restrict__ causal_p)
{
    __shared__ __align__(16) u16 Qs[64][72];
    __shared__ __align__(16) u16 Ks[64][72];
    __shared__ __align__(16) u16 Vt[64][72];   // transposed: [d][key^swz]
    __shared__ __align__(16) u16 Ps[64][72];

    const int tid  = threadIdx.x;
    const int lane = tid & 63;
    const int wv   = tid >> 6;
    const int ln   = lane & 15, lh = lane >> 4;
    const int bh   = blockIdx.x;                // b*16 + h
    const int pr   = blockIdx.y;                // 0..15
    const int b    = bh >> 4;
    const int h    = bh & 15;
    const int causal = causal_p[0];

    const float SCL = 11.5415600372f;           // 8 * log2(e)
    const float MSK = 1442695.04f;              // 1e6 * log2(e)

    const u16* Qg = Q + (size_t)bh * TSEQ * DHEAD;
    const u16* Kg = K + (size_t)bh * TSEQ * DHEAD;
    const u16* Vg = V + (size_t)bh * TSEQ * DHEAD;

    const int lrow = tid >> 3;                  // 0..31
    const int lc8  = (tid & 7) * 8;

    for (int half = 0; half < 2; ++half) {
        const int qb     = half ? (NQB - 1 - pr) : pr;
        const int kb_end = causal ? qb : (NQB - 1);

        __syncthreads();     // prior tile's LDS fully consumed

        // Q tile -> LDS; prefetch K/V block 0 into regs
        *(uint4*)&Qs[lrow][lc8]      = *(const uint4*)(Qg + (size_t)(qb * 64 + lrow) * DHEAD + lc8);
        *(uint4*)&Qs[lrow + 32][lc8] = *(const uint4*)(Qg + (size_t)(qb * 64 + lrow + 32) * DHEAD + lc8);
        uint4 kreg0 = *(const uint4*)(Kg + (size_t)lrow * DHEAD + lc8);
        uint4 kreg1 = *(const uint4*)(Kg + (size_t)(lrow + 32) * DHEAD + lc8);
        uint4 vreg0 = *(const uint4*)(Vg + (size_t)lrow * DHEAD + lc8);
        uint4 vreg1 = *(const uint4*)(Vg + (size_t)(lrow + 32) * DHEAD + lc8);
        __syncthreads();

        const int qr0 = wv * 16;
        const half8 aQ0 = *(const half8*)&Qs[qr0 + ln][lh * 8];
        const half8 aQ1 = *(const half8*)&Qs[qr0 + ln][32 + lh * 8];

        const floatx4 zero4 = {0.0f, 0.0f, 0.0f, 0.0f};
        floatx4 o[4];
#pragma unroll
        for (int j = 0; j < 4; ++j) o[j] = zero4;
        float m_i[4], l_i[4];
#pragma unroll
        for (int r = 0; r < 4; ++r) { m_i[r] = -3.0e38f; l_i[r] = 0.0f; }

        for (int kb = 0; kb <= kb_end; ++kb) {
            // stage prefetched regs -> LDS (K row-major, V transposed+swizzled)
            *(uint4*)&Ks[lrow][lc8]      = kreg0;
            *(uint4*)&Ks[lrow + 32][lc8] = kreg1;
            {
                const u16* pv = (const u16*)&vreg0;
#pragma unroll
                for (int e = 0; e < 8; ++e) {
                    const int rr = lc8 + e;
                    Vt[rr][lrow ^ ((rr >> 3) << 3)] = pv[e];
                }
                const u16* pw = (const u16*)&vreg1;
#pragma unroll
                for (int e = 0; e < 8; ++e) {
                    const int rr = lc8 + e;
                    Vt[rr][(lrow + 32) ^ ((rr >> 3) << 3)] = pw[e];
                }
            }
            __syncthreads();       // K/V tile ready

            // prefetch next K/V block (latency hidden behind compute below)
            if (kb < kb_end) {
                const size_t nb = (size_t)(kb + 1) * 64;
                kreg0 = *(const uint4*)(Kg + (nb + lrow) * DHEAD + lc8);
                kreg1 = *(const uint4*)(Kg + (nb + lrow + 32) * DHEAD + lc8);
                vreg0 = *(const uint4*)(Vg + (nb + lrow) * DHEAD + lc8);
                vreg1 = *(const uint4*)(Vg + (nb + lrow + 32) * DHEAD + lc8);
            }

            // S = Q K^T (pre-scaled into exp2 domain)
            floatx4 s[4];
#pragma unroll
            for (int j = 0; j < 4; ++j) {
                half8 bk0 = *(const half8*)&Ks[j * 16 + ln][lh * 8];
                half8 bk1 = *(const half8*)&Ks[j * 16 + ln][32 + lh * 8];
                floatx4 z = zero4;
                z = __builtin_amdgcn_mfma_f32_16x16x32_f16(aQ0, bk0, z, 0, 0, 0);
                z = __builtin_amdgcn_mfma_f32_16x16x32_f16(aQ1, bk1, z, 0, 0, 0);
                s[j] = z;
            }
            const bool diag = (causal != 0) && (kb == qb);
            float sv[4][4];
#pragma unroll
            for (int j = 0; j < 4; ++j)
#pragma unroll
                for (int r = 0; r < 4; ++r) {
                    float x = s[j][r] * SCL;
                    if (diag && (j * 16 + ln > qr0 + lh * 4 + r)) x -= MSK;
                    sv[j][r] = x;
                }

            // online softmax (rows in lane>>4 groups; 16-lane shuffles)
            float mnew[4], alpha[4];
#pragma unroll
            for (int r = 0; r < 4; ++r) {
                float mx = m_i[r];
#pragma unroll
                for (int j = 0; j < 4; ++j) mx = fmaxf(mx, sv[j][r]);
                mx = rmax16(mx);
                mnew[r]  = mx;
                alpha[r] = exp2f(m_i[r] - mx);
                m_i[r]   = mx;
            }
            float p[4][4];
#pragma unroll
            for (int j = 0; j < 4; ++j)
#pragma unroll
                for (int r = 0; r < 4; ++r) p[j][r] = exp2f(sv[j][r] - mnew[r]);
#pragma unroll
            for (int r = 0; r < 4; ++r) {
                float t = p[0][r] + p[1][r] + p[2][r] + p[3][r];
                t = rsum16(t);
                l_i[r] = l_i[r] * alpha[r] + t;
            }
#pragma unroll
            for (int j = 0; j < 4; ++j)
#pragma unroll
                for (int r = 0; r < 4; ++r) o[j][r] *= alpha[r];

            // P: C-layout -> LDS (wave-private rows; no barrier needed)
#pragma unroll
            for (int j = 0; j < 4; ++j)
#pragma unroll
                for (int r = 0; r < 4; ++r)
                    Ps[qr0 + lh * 4 + r][j * 16 + ln] = f2h(p[j][r]);

            half8 aP0 = *(const half8*)&Ps[qr0 + ln][lh * 8];
            half8 aP1 = *(const half8*)&Ps[qr0 + ln][32 + lh * 8];

            // O += P V
#pragma unroll
            for (int j = 0; j < 4; ++j) {
                const int rowd = j * 16 + ln;
                const int sw   = (rowd >> 3) << 3;
                half8 bv0 = *(const half8*)&Vt[rowd][(lh * 8) ^ sw];
                half8 bv1 = *(const half8*)&Vt[rowd][(32 + lh * 8) ^ sw];
                o[j] = __builtin_amdgcn_mfma_f32_16x16x32_f16(aP0, bv0, o[j], 0, 0, 0);
                o[j] = __builtin_amdgcn_mfma_f32_16x16x32_f16(aP1, bv1, o[j], 0, 0, 0);
            }
            __syncthreads();   // all reads of Ks/Vt done before next staging
        }

        // epilogue: AV[t][b][h*64+d] fp16 rows for the out-proj GEMM
#pragma unroll
        for (int r = 0; r < 4; ++r) {
            const float il = 1.0f / l_i[r];
            const int qrow = qb * 64 + qr0 + lh * 4 + r;
#pragma unroll
            for (int j = 0; j < 4; ++j) {
                const int d = j * 16 + ln;
                AV[((size_t)qrow * BB + b) * DMODEL + h * 64 + d] = f2h(o[j][r] * il);
            }
        }
    }
}

// ---------------------------------------------------------------------------
extern "C" void kernel_launch(void* const* d_in, const int* in_sizes, int n_in,
                              void* d_out, int out_size, void* d_ws, size_t ws_size,
                              hipStream_t stream)
{
    const float* x      = (const float*)d_in[0];
    const float* qkv_w  = (const float*)d_in[1];
    const float* qkv_b  = (const float*)d_in[2];
    const float* out_w  = (const float*)d_in[3];
    const float* out_b  = (const float*)d_in[4];
    const int*   is_causal = (const int*)d_in[5];
    float* out = (float*)d_out;

    u16* ws   = (u16*)d_ws;
    u16* xb   = ws;                       // 4096*1024
    u16* wqkv = xb   + (size_t)4194304;   // 3072*1024
    u16* wout = wqkv + (size_t)3145728;   // 1024*1024
    u16* Qh   = wout + (size_t)1048576;   // 2*16*2048*64
    u16* Kh   = Qh   + (size_t)4194304;
    u16* Vh   = Kh   + (size_t)4194304;
    u16* AVh  = Vh   + (size_t)4194304;   // 4096*1024

    cast3_f32_f16<<<8192, 256, 0, stream>>>(x, xb, qkv_w, wqkv, out_w, wout);

    // QKV projection: M=4096, N=3072, K=1024 (scatter epilogue)
    gemm_f16<<<dim3(3 * DMODEL / 128, MROWS / 128), 256, 0, stream>>>(
        xb, wqkv, qkv_b, nullptr, Qh, Kh, Vh, MROWS, 3 * DMODEL, DMODEL, 1);

    // flash attention: grid (B*H, NQB/2) paired q-tiles
    flash_f16<<<dim3(BB * NHEAD, NQB / 2), 256, 0, stream>>>(
        Qh, Kh, Vh, AVh, is_causal);

    // output projection: M=4096, N=1024, K=1024 (fp32 out)
    gemm_f16<<<dim3(DMODEL / 128, MROWS / 128), 256, 0, stream>>>(
        AVh, wout, out_b, out, nullptr, nullptr, nullptr, MROWS, DMODEL, DMODEL, 0);
}